// Round 12
// baseline (133.983 us; speedup 1.0000x reference)
//
#include <hip/hip_runtime.h>
#include <hip/hip_fp16.h>
#include <math.h>

// Padded LDS index for FFT scratch: injective for e in [0,256) -> [0,271)
#define PIDX(e) ((e) + ((e) >> 4))

#define N_IMG 288
#define COLBLK_TOTAL (8 * N_IMG)  // colfft block count (all batches)

// Wave-local "sync": waves own disjoint LDS slices; same-wave DS ops are
// processed in order by the LDS pipe, so we only need a COMPILER fence.
#define WAVE_SYNC()                          \
    do {                                     \
        __builtin_amdgcn_wave_barrier();     \
        asm volatile("" ::: "memory");       \
    } while (0)

__device__ __forceinline__ float2 cadd(float2 a, float2 b) { return {a.x + b.x, a.y + b.y}; }
__device__ __forceinline__ float2 csub(float2 a, float2 b) { return {a.x - b.x, a.y - b.y}; }
__device__ __forceinline__ float2 cmul(float2 a, float2 b) {
    return {a.x * b.x - a.y * b.y, a.x * b.y + a.y * b.x};
}
__device__ __forceinline__ float2 shfl64(float2 v, int src) {
    return {__shfl(v.x, src), __shfl(v.y, src)};
}

// Radix-4 butterfly (DIF): d0..d3 from c0..c3.
#define BFLY4(c0, c1, c2, c3, d0, d1, d2, d3)            \
    {                                                    \
        float2 sa = cadd(c0, c2);                        \
        float2 sb = csub(c0, c2);                        \
        float2 sc = cadd(c1, c3);                        \
        float2 sd = {(c1).y - (c3).y, (c3).x - (c1).x}; \
        d0 = cadd(sa, sc);                               \
        d1 = cadd(sb, sd);                               \
        d2 = csub(sa, sc);                               \
        d3 = csub(sb, sd);                               \
    }

// Per-lane twiddle set for one stage (constant across all FFTs of the kernel).
struct Tw {
    float2 w1, w2, w3;
};
__device__ __forceinline__ Tw make_tw(int idx) {
    const float ang = -0.024543692606170259f * (float)idx;  // -(2pi/256)*idx
    float sy, cx;
    __sincosf(ang, &sy, &cx);
    Tw tw;
    tw.w1 = {cx, sy};
    tw.w2 = cmul(tw.w1, tw.w1);
    tw.w3 = cmul(tw.w2, tw.w1);
    return tw;
}

// Stage 0 (stride-64 partners, within-lane): registers -> LDS (natural order).
__device__ __forceinline__ void fft_stage0(float2 z0, float2 z1, float2 z2, float2 z3, float2* X,
                                           int t, const Tw& tw) {
    float2 d0, d1, d2, d3;
    BFLY4(z0, z1, z2, z3, d0, d1, d2, d3);
    const int ob = t << 2;
    X[PIDX(ob)] = d0;
    X[PIDX(ob + 1)] = cmul(tw.w1, d1);
    X[PIDX(ob + 2)] = cmul(tw.w2, d2);
    X[PIDX(ob + 3)] = cmul(tw.w3, d3);
    WAVE_SYNC();
}

// Middle stage (s=1: SH=2, s=2: SH=4), single LDS buffer: reads are always
// {t, t+64, t+128, t+192}; read-all -> fence -> write-all (same-wave DS order).
template <int SH>
__device__ __forceinline__ void fft_stage_mid(float2* X, int t, const Tw& tw) {
    float2 c0 = X[PIDX(t)];
    float2 c1 = X[PIDX(t + 64)];
    float2 c2 = X[PIDX(t + 128)];
    float2 c3 = X[PIDX(t + 192)];
    WAVE_SYNC();
    float2 d0, d1, d2, d3;
    BFLY4(c0, c1, c2, c3, d0, d1, d2, d3);
    const int mm = 1 << SH;
    const int jj = t >> SH;
    const int kk = t & (mm - 1);
    const int ob = kk + 4 * mm * jj;
    X[PIDX(ob)] = d0;
    X[PIDX(ob + mm)] = cmul(tw.w1, d1);
    X[PIDX(ob + 2 * mm)] = cmul(tw.w2, d2);
    X[PIDX(ob + 3 * mm)] = cmul(tw.w3, d3);
    WAVE_SYNC();
}

// Stage 3 (jj=0 -> identity twiddle): keep the result in registers.
// d_q = Z[t + 64q].
__device__ __forceinline__ void fft_stage3_reg(float2* X, int t, float2& d0, float2& d1,
                                               float2& d2, float2& d3) {
    float2 c0 = X[PIDX(t)];
    float2 c1 = X[PIDX(t + 64)];
    float2 c2 = X[PIDX(t + 128)];
    float2 c3 = X[PIDX(t + 192)];
    WAVE_SYNC();  // reads done before this buffer is overwritten by next stage0
    BFLY4(c0, c1, c2, c3, d0, d1, d2, d3);
}

// 16 strided dword loads: lane t gets element cols {t+64q} of rows r, r+1 for
// both inputs. Each instr reads 256B contiguous across the wave (coalesced).
__device__ __forceinline__ void load16(const float* __restrict__ abase,
                                       const float* __restrict__ sbase, int r, int t, float* a0,
                                       float* a1, float* s0, float* s1) {
#pragma unroll
    for (int q = 0; q < 4; ++q) {
        a0[q] = abase[(r << 8) + t + (q << 6)];
        a1[q] = abase[((r + 1) << 8) + t + (q << 6)];
        s0[q] = sbase[(r << 8) + t + (q << 6)];
        s1[q] = sbase[((r + 1) << 8) + t + (q << 6)];
    }
}

// Kernel 1: row FFTs of the real difference image, two rows per complex FFT.
// Output f16 spectra transposed [img][v][r], v in [0,128): v=0 packs (D[0],D[128]).
// grid = (8 row-chunks, nimg), block = 512 = 8 waves; 2 packed FFTs per wave,
// register prefetch, stage0+stage3 in registers, hoisted twiddles.
// Also zeroes the colfft ready-counter (first block of first batch).
__global__ __launch_bounds__(512, 8) void k_rowfft(const float* __restrict__ A,
                                                   const float* __restrict__ P,
                                                   const float* __restrict__ N,
                                                   const int* __restrict__ negIdx,
                                                   __half2* __restrict__ ws, int img0,
                                                   int* __restrict__ counter) {
    __shared__ float2 Xb[8][272];       // 17.4 KB (single-buffer FFT)
    __shared__ __half2 outT[128 * 33];  // 16.9 KB, stride 33 -> conflict-free

    if (img0 == 0 && blockIdx.x == 0 && blockIdx.y == 0 && threadIdx.x == 0) *counter = 0;

    const int img = img0 + blockIdx.y;
    const int pair = img / 3;
    const int ch = img - pair * 3;
    int i, jn;
    const float* S;
    if (pair < 32) {  // anchor-positive pairs: j == i
        i = pair;
        jn = pair;
        S = P;
    } else {  // anchor-negative pairs: j = neg_idx[i][k]
        const int t2 = pair - 32;
        i = t2 >> 1;
        jn = negIdx[(i << 1) + (t2 & 1)];
        S = N;
    }
    const float* abase = A + ((size_t)(i * 3 + ch) << 16);
    const float* sbase = S + ((size_t)(jn * 3 + ch) << 16);

    const int tid = threadIdx.x;
    const int w = tid >> 6;   // wave id [0,8)
    const int t = tid & 63;   // lane
    const int r0 = blockIdx.x * 32;

    // Hoisted per-lane twiddles (constant for every FFT in this kernel).
    const Tw tw0 = make_tw(t);
    const Tw tw1 = make_tw(t & ~3);
    const Tw tw2 = make_tw(t & ~15);
    const int ridx = (64 - t) & 63;  // reversal shuffle index

    float pa0[4], pa1[4], ps0[4], ps1[4];
    load16(abase, sbase, r0 + 2 * w, t, pa0, pa1, ps0, ps1);

    for (int it = 0; it < 2; ++it) {
        const int slot = 2 * (it * 8 + w);  // even row slot in [0,32)
        float2 z[4];
#pragma unroll
        for (int q = 0; q < 4; ++q) z[q] = {pa0[q] - ps0[q], pa1[q] - ps1[q]};
        // prefetch next iteration's rows; flies under the whole FFT
        if (it < 1) load16(abase, sbase, r0 + 2 * ((it + 1) * 8 + w), t, pa0, pa1, ps0, ps1);
        fft_stage0(z[0], z[1], z[2], z[3], Xb[w], t, tw0);
        fft_stage_mid<2>(Xb[w], t, tw1);
        fft_stage_mid<4>(Xb[w], t, tw2);
        float2 d0, d1, d2, d3;  // d_q = Z[t + 64q]
        fft_stage3_reg(Xb[w], t, d0, d1, d2, d3);
        // Hermitian unpack (register/shuffle only):
        //   D_r[v] = 0.5*(Z[v] + conj(Z[-v]));  D_r1[v] = -0.5i*(Z[v] - conj(Z[-v]))
        const float2 m3 = shfl64(d3, ridx);  // Z[256-t] for t>=1
        const float2 m2 = shfl64(d2, ridx);  // Z[192-t] for t>=1
        if (t == 0) {
            // v=0 packs (D_r[0], D_r[128]) = (Re/Im Z[0], Re/Im Z[128])
            outT[slot] = __floats2half2_rn(d0.x, d2.x);
            outT[slot + 1] = __floats2half2_rn(d0.y, d2.y);
        } else {
            outT[t * 33 + slot] = __floats2half2_rn(0.5f * (d0.x + m3.x), 0.5f * (d0.y - m3.y));
            outT[t * 33 + slot + 1] =
                __floats2half2_rn(0.5f * (d0.y + m3.y), -0.5f * (d0.x - m3.x));
        }
        {  // v = t + 64;  m = Z[192-t] (lane 0: Z[192] = own d3)
            const int v = t + 64;
            const float2 mm2 = (t == 0) ? d3 : m2;
            outT[v * 33 + slot] = __floats2half2_rn(0.5f * (d1.x + mm2.x), 0.5f * (d1.y - mm2.y));
            outT[v * 33 + slot + 1] =
                __floats2half2_rn(0.5f * (d1.y + mm2.y), -0.5f * (d1.x - mm2.x));
        }
        WAVE_SYNC();  // outT slot writes complete before Xb reuse next iter
    }

    __syncthreads();  // all waves' outT slots complete

    // write [v][r0..r0+31] chunks: one float4 (4 half2) per thread per iter
    __half2* g = ws + (size_t)blockIdx.y * (128 * 256);
    for (int e = tid; e < 128 * 8; e += 512) {
        const int v = e >> 3, rl4 = (e & 7) << 2;
        float4 val;
        __half2* vp = (__half2*)&val;
#pragma unroll
        for (int k = 0; k < 4; ++k) vp[k] = outT[v * 33 + rl4 + k];
        *(float4*)(g + v * 256 + r0 + rl4) = val;
    }
}

// Kernel 2: column FFTs (complex 256-pt) + weighted magnitude sum.
// grid = (8, nimg), block = 256 = 4 waves; each wave owns 4 consecutive
// columns serially with register prefetch; stages 0 & 3 in registers,
// magnitudes own-lane (LDS-free) except the rare v==0 wave.
// v=0 is the packed real pair (col0, col128): weight 1; v>=1: weight 2.
// LAST block (device counter) performs the final deterministic reduction.
__global__ __launch_bounds__(256) void k_colfft(const __half2* __restrict__ ws,
                                                float* __restrict__ partial, int img0,
                                                int* __restrict__ counter,
                                                float* __restrict__ out) {
    __shared__ float2 Xb[4][272];  // 8.7 KB
    __shared__ float wsum[4];
    __shared__ int isLast;
    const int tid = threadIdx.x;
    const int w = tid >> 6, t = tid & 63;
    const int vbase = blockIdx.x * 16 + w * 4;  // [0,128)
    const __half2* gimg = ws + (size_t)blockIdx.y * (128 * 256);

    const Tw tw0 = make_tw(t);
    const Tw tw1 = make_tw(t & ~3);
    const Tw tw2 = make_tw(t & ~15);

    float acc = 0.f;
    __half2 cur[4], nxt[4];
#pragma unroll
    for (int q = 0; q < 4; ++q) cur[q] = gimg[(size_t)vbase * 256 + t + (q << 6)];
    for (int j = 0; j < 4; ++j) {
        const int v = vbase + j;
        if (j < 3) {
#pragma unroll
            for (int q = 0; q < 4; ++q) nxt[q] = gimg[(size_t)(v + 1) * 256 + t + (q << 6)];
        }
        float2 z[4];
#pragma unroll
        for (int q = 0; q < 4; ++q) z[q] = __half22float2(cur[q]);
        fft_stage0(z[0], z[1], z[2], z[3], Xb[w], t, tw0);
        fft_stage_mid<2>(Xb[w], t, tw1);
        fft_stage_mid<4>(Xb[w], t, tw2);
        float2 d0, d1, d2, d3;  // d_q = W[t + 64q]
        fft_stage3_reg(Xb[w], t, d0, d1, d2, d3);
        float ssum = 0.f;
        if (v == 0) {  // wave-uniform rare path: needs W[-u]; LDS round trip
            Xb[w][PIDX(t)] = d0;
            Xb[w][PIDX(t + 64)] = d1;
            Xb[w][PIDX(t + 128)] = d2;
            Xb[w][PIDX(t + 192)] = d3;
            WAVE_SYNC();
#pragma unroll
            for (int q = 0; q < 4; ++q) {
                const int u = t + 64 * q;
                const float2 zu = Xb[w][PIDX(u)];
                const float2 zm = Xb[w][PIDX((256 - u) & 255)];
                // C_A[u] = 0.5(W[u]+conj(W[-u]));  C_B[u] = -0.5i(W[u]-conj(W[-u]))
                const float ax = 0.5f * (zu.x + zm.x), ay = 0.5f * (zu.y - zm.y);
                const float bx = 0.5f * (zu.y + zm.y), by = -0.5f * (zu.x - zm.x);
                ssum += sqrtf(ax * ax + ay * ay) + sqrtf(bx * bx + by * by);
            }
        } else {
            ssum = 2.f * (sqrtf(d0.x * d0.x + d0.y * d0.y) + sqrtf(d1.x * d1.x + d1.y * d1.y) +
                          sqrtf(d2.x * d2.x + d2.y * d2.y) + sqrtf(d3.x * d3.x + d3.y * d3.y));
        }
        acc += ssum;
#pragma unroll
        for (int q = 0; q < 4; ++q) cur[q] = nxt[q];
        WAVE_SYNC();  // Xb fully consumed before next column's stage-0 writes
    }
#pragma unroll
    for (int off = 32; off; off >>= 1) acc += __shfl_down(acc, off);
    if (t == 0) wsum[w] = acc;
    __syncthreads();
    if (tid == 0) {
        const int img = img0 + blockIdx.y;
        partial[img * 8 + blockIdx.x] = wsum[0] + wsum[1] + wsum[2] + wsum[3];
        __threadfence();  // release partial before counting
        const int old = atomicAdd(counter, 1);
        isLast = (old == COLBLK_TOTAL - 1) ? 1 : 0;
    }
    __syncthreads();
    // Final reduction by the single last-arriving block (deterministic order).
    if (isLast) {
        __shared__ float ps[96];
        if (tid == 0) __threadfence();  // acquire all partials
        __syncthreads();
        if (tid < 96) {
            float s = 0.f;
            const float* p = partial + tid * 24;  // pair tid/... : imgs 3p..3p+2, 8 chunks each
            for (int e = 0; e < 24; ++e) s += p[e];
            ps[tid] = s;
        }
        __syncthreads();
        if (tid < 64) {  // wave 0: tid = 2i+k
            const float inv = 1.f / 196608.f;  // mean over C*H*W
            const float dap = ps[tid >> 1] * inv;
            const float dan = ps[32 + tid] * inv + 1e-7f;
            float val = dap / dan;
#pragma unroll
            for (int off = 32; off; off >>= 1) val += __shfl_down(val, off);
            if (tid == 0) out[0] = val * (1.f / 64.f);  // / (MULTI_N_NUM * B)
        }
    }
}

extern "C" void kernel_launch(void* const* d_in, const int* in_sizes, int n_in,
                              void* d_out, int out_size, void* d_ws, size_t ws_size,
                              hipStream_t stream) {
    const float* A = (const float*)d_in[0];
    const float* P = (const float*)d_in[1];
    const float* N = (const float*)d_in[2];
    const int* negIdx = (const int*)d_in[3];

    float* partial = (float*)d_ws;                    // 2304 floats = 9216 B
    int* counter = (int*)((char*)d_ws + 9216);        // 4 B
    __half2* inter = (__half2*)((char*)d_ws + 40960);
    const size_t perImg = (size_t)128 * 256 * sizeof(__half2);  // 131072 B
    size_t avail = ws_size > 40960 ? ws_size - 40960 : 0;
    int cap = (int)(avail / perImg);
    if (cap > N_IMG) cap = N_IMG;
    if (cap < 1) cap = 1;  // last resort

    for (int img0 = 0; img0 < N_IMG; img0 += cap) {
        const int nimg = (N_IMG - img0 < cap) ? (N_IMG - img0) : cap;
        dim3 g1(8, nimg);
        k_rowfft<<<g1, dim3(512), 0, stream>>>(A, P, N, negIdx, inter, img0, counter);
        dim3 g2(8, nimg);
        k_colfft<<<g2, dim3(256), 0, stream>>>(inter, partial, img0, counter, (float*)d_out);
    }
}

// Round 14
// 93.983 us; speedup vs baseline: 1.4256x; 1.4256x over previous
//
#include <hip/hip_runtime.h>
#include <hip/hip_fp16.h>
#include <math.h>

// Padded LDS index for FFT scratch: injective for e in [0,256) -> [0,271)
#define PIDX(e) ((e) + ((e) >> 4))

#define N_IMG 288
#define COLBLK_TOTAL (8 * N_IMG)  // colfft block count (all batches)

// Wave-local "sync": waves own disjoint LDS slices; same-wave DS ops are
// processed in order by the LDS pipe, so we only need a COMPILER fence.
#define WAVE_SYNC()                          \
    do {                                     \
        __builtin_amdgcn_wave_barrier();     \
        asm volatile("" ::: "memory");       \
    } while (0)

__device__ __forceinline__ float2 cadd(float2 a, float2 b) { return {a.x + b.x, a.y + b.y}; }
__device__ __forceinline__ float2 csub(float2 a, float2 b) { return {a.x - b.x, a.y - b.y}; }
__device__ __forceinline__ float2 cmul(float2 a, float2 b) {
    return {a.x * b.x - a.y * b.y, a.x * b.y + a.y * b.x};
}
__device__ __forceinline__ float2 shfl64(float2 v, int src) {
    return {__shfl(v.x, src), __shfl(v.y, src)};
}

// Radix-4 butterfly (DIF): d0..d3 from c0..c3.
#define BFLY4(c0, c1, c2, c3, d0, d1, d2, d3)            \
    {                                                    \
        float2 sa = cadd(c0, c2);                        \
        float2 sb = csub(c0, c2);                        \
        float2 sc = cadd(c1, c3);                        \
        float2 sd = {(c1).y - (c3).y, (c3).x - (c1).x}; \
        d0 = cadd(sa, sc);                               \
        d1 = cadd(sb, sd);                               \
        d2 = csub(sa, sc);                               \
        d3 = csub(sb, sd);                               \
    }

// Per-lane twiddle set for one stage (constant across all FFTs of the kernel).
struct Tw {
    float2 w1, w2, w3;
};
__device__ __forceinline__ Tw make_tw(int idx) {
    const float ang = -0.024543692606170259f * (float)idx;  // -(2pi/256)*idx
    float sy, cx;
    __sincosf(ang, &sy, &cx);
    Tw tw;
    tw.w1 = {cx, sy};
    tw.w2 = cmul(tw.w1, tw.w1);
    tw.w3 = cmul(tw.w2, tw.w1);
    return tw;
}

// Stage 0 (stride-64 partners, within-lane): registers -> LDS (natural order).
__device__ __forceinline__ void fft_stage0(float2 z0, float2 z1, float2 z2, float2 z3, float2* X,
                                           int t, const Tw& tw) {
    float2 d0, d1, d2, d3;
    BFLY4(z0, z1, z2, z3, d0, d1, d2, d3);
    const int ob = t << 2;
    X[PIDX(ob)] = d0;
    X[PIDX(ob + 1)] = cmul(tw.w1, d1);
    X[PIDX(ob + 2)] = cmul(tw.w2, d2);
    X[PIDX(ob + 3)] = cmul(tw.w3, d3);
    WAVE_SYNC();
}

// Middle stage (s=1: SH=2, s=2: SH=4), single LDS buffer: reads are always
// {t, t+64, t+128, t+192}; read-all -> fence -> write-all (same-wave DS order).
template <int SH>
__device__ __forceinline__ void fft_stage_mid(float2* X, int t, const Tw& tw) {
    float2 c0 = X[PIDX(t)];
    float2 c1 = X[PIDX(t + 64)];
    float2 c2 = X[PIDX(t + 128)];
    float2 c3 = X[PIDX(t + 192)];
    WAVE_SYNC();
    float2 d0, d1, d2, d3;
    BFLY4(c0, c1, c2, c3, d0, d1, d2, d3);
    const int mm = 1 << SH;
    const int jj = t >> SH;
    const int kk = t & (mm - 1);
    const int ob = kk + 4 * mm * jj;
    X[PIDX(ob)] = d0;
    X[PIDX(ob + mm)] = cmul(tw.w1, d1);
    X[PIDX(ob + 2 * mm)] = cmul(tw.w2, d2);
    X[PIDX(ob + 3 * mm)] = cmul(tw.w3, d3);
    WAVE_SYNC();
}

// Stage 3 (jj=0 -> identity twiddle): keep the result in registers.
// d_q = Z[t + 64q].
__device__ __forceinline__ void fft_stage3_reg(float2* X, int t, float2& d0, float2& d1,
                                               float2& d2, float2& d3) {
    float2 c0 = X[PIDX(t)];
    float2 c1 = X[PIDX(t + 64)];
    float2 c2 = X[PIDX(t + 128)];
    float2 c3 = X[PIDX(t + 192)];
    WAVE_SYNC();  // reads done before this buffer is overwritten by next stage0
    BFLY4(c0, c1, c2, c3, d0, d1, d2, d3);
}

// 16 strided dword loads: lane t gets element cols {t+64q} of rows r, r+1 for
// both inputs. Each instr reads 256B contiguous across the wave (coalesced).
__device__ __forceinline__ void load16(const float* __restrict__ abase,
                                       const float* __restrict__ sbase, int r, int t, float* a0,
                                       float* a1, float* s0, float* s1) {
#pragma unroll
    for (int q = 0; q < 4; ++q) {
        a0[q] = abase[(r << 8) + t + (q << 6)];
        a1[q] = abase[((r + 1) << 8) + t + (q << 6)];
        s0[q] = sbase[(r << 8) + t + (q << 6)];
        s1[q] = sbase[((r + 1) << 8) + t + (q << 6)];
    }
}

// Kernel 1: row FFTs of the real difference image, two rows per complex FFT.
// Output f16 spectra transposed [img][v][r], v in [0,128): v=0 packs (D[0],D[128]).
// grid = (8 row-chunks, nimg), block = 256 = 4 waves; 4 packed FFTs per wave,
// register prefetch, stage0+stage3 in registers, hoisted twiddles.
// First block of first batch zeroes the colfft ready-counter.
__global__ __launch_bounds__(256) void k_rowfft(const float* __restrict__ A,
                                                const float* __restrict__ P,
                                                const float* __restrict__ N,
                                                const int* __restrict__ negIdx,
                                                __half2* __restrict__ ws, int img0,
                                                int* __restrict__ counter) {
    __shared__ float2 Xb[4][272];       // 8.7 KB (single-buffer FFT)
    __shared__ __half2 outT[128 * 33];  // 16.9 KB, stride 33 -> conflict-free

    if (img0 == 0 && blockIdx.x == 0 && blockIdx.y == 0 && threadIdx.x == 0) *counter = 0;

    const int img = img0 + blockIdx.y;
    const int pair = img / 3;
    const int ch = img - pair * 3;
    int i, jn;
    const float* S;
    if (pair < 32) {  // anchor-positive pairs: j == i
        i = pair;
        jn = pair;
        S = P;
    } else {  // anchor-negative pairs: j = neg_idx[i][k]
        const int t2 = pair - 32;
        i = t2 >> 1;
        jn = negIdx[(i << 1) + (t2 & 1)];
        S = N;
    }
    const float* abase = A + ((size_t)(i * 3 + ch) << 16);
    const float* sbase = S + ((size_t)(jn * 3 + ch) << 16);

    const int tid = threadIdx.x;
    const int w = tid >> 6;   // wave id
    const int t = tid & 63;   // lane
    const int r0 = blockIdx.x * 32;

    // Hoisted per-lane twiddles (constant for every FFT in this kernel).
    const Tw tw0 = make_tw(t);
    const Tw tw1 = make_tw(t & ~3);
    const Tw tw2 = make_tw(t & ~15);
    const int ridx = (64 - t) & 63;  // reversal shuffle index

    float pa0[4], pa1[4], ps0[4], ps1[4];
    load16(abase, sbase, r0 + 2 * w, t, pa0, pa1, ps0, ps1);

    for (int it = 0; it < 4; ++it) {
        const int slot = 2 * (it * 4 + w);  // even row slot in [0,32)
        float2 z[4];
#pragma unroll
        for (int q = 0; q < 4; ++q) z[q] = {pa0[q] - ps0[q], pa1[q] - ps1[q]};
        // prefetch next iteration's rows; flies under the whole FFT
        if (it < 3) load16(abase, sbase, r0 + 2 * ((it + 1) * 4 + w), t, pa0, pa1, ps0, ps1);
        fft_stage0(z[0], z[1], z[2], z[3], Xb[w], t, tw0);
        fft_stage_mid<2>(Xb[w], t, tw1);
        fft_stage_mid<4>(Xb[w], t, tw2);
        float2 d0, d1, d2, d3;  // d_q = Z[t + 64q]
        fft_stage3_reg(Xb[w], t, d0, d1, d2, d3);
        // Hermitian unpack (register/shuffle only):
        //   D_r[v] = 0.5*(Z[v] + conj(Z[-v]));  D_r1[v] = -0.5i*(Z[v] - conj(Z[-v]))
        const float2 m3 = shfl64(d3, ridx);  // Z[256-t] for t>=1
        const float2 m2 = shfl64(d2, ridx);  // Z[192-t] for t>=1
        if (t == 0) {
            // v=0 packs (D_r[0], D_r[128]) = (Re/Im Z[0], Re/Im Z[128])
            outT[slot] = __floats2half2_rn(d0.x, d2.x);
            outT[slot + 1] = __floats2half2_rn(d0.y, d2.y);
        } else {
            outT[t * 33 + slot] = __floats2half2_rn(0.5f * (d0.x + m3.x), 0.5f * (d0.y - m3.y));
            outT[t * 33 + slot + 1] =
                __floats2half2_rn(0.5f * (d0.y + m3.y), -0.5f * (d0.x - m3.x));
        }
        {  // v = t + 64;  m = Z[192-t] (lane 0: Z[192] = own d3)
            const int v = t + 64;
            const float2 mm2 = (t == 0) ? d3 : m2;
            outT[v * 33 + slot] = __floats2half2_rn(0.5f * (d1.x + mm2.x), 0.5f * (d1.y - mm2.y));
            outT[v * 33 + slot + 1] =
                __floats2half2_rn(0.5f * (d1.y + mm2.y), -0.5f * (d1.x - mm2.x));
        }
        WAVE_SYNC();  // outT slot writes complete before Xb reuse next iter
    }

    __syncthreads();  // all waves' outT slots complete

    // write [v][r0..r0+31] chunks: one float4 (4 half2) per thread per iter
    __half2* g = ws + (size_t)blockIdx.y * (128 * 256);
    for (int e = tid; e < 128 * 8; e += 256) {
        const int v = e >> 3, rl4 = (e & 7) << 2;
        float4 val;
        __half2* vp = (__half2*)&val;
#pragma unroll
        for (int k = 0; k < 4; ++k) vp[k] = outT[v * 33 + rl4 + k];
        *(float4*)(g + v * 256 + r0 + rl4) = val;
    }
}

// Kernel 2: column FFTs (complex 256-pt) + weighted magnitude sum.
// grid = (8, nimg), block = 256 = 4 waves; each wave owns 4 consecutive
// columns serially with register prefetch; stages 0 & 3 in registers,
// magnitudes own-lane (LDS-free) except the rare v==0 wave.
// v=0 is the packed real pair (col0, col128): weight 1; v>=1: weight 2.
// LAST block (device counter) performs the final deterministic reduction.
__global__ __launch_bounds__(256) void k_colfft(const __half2* __restrict__ ws,
                                                float* __restrict__ partial, int img0,
                                                int* __restrict__ counter,
                                                float* __restrict__ out) {
    __shared__ float2 Xb[4][272];  // 8.7 KB
    __shared__ float wsum[4];
    __shared__ int isLast;
    const int tid = threadIdx.x;
    const int w = tid >> 6, t = tid & 63;
    const int vbase = blockIdx.x * 16 + w * 4;  // [0,128)
    const __half2* gimg = ws + (size_t)blockIdx.y * (128 * 256);

    const Tw tw0 = make_tw(t);
    const Tw tw1 = make_tw(t & ~3);
    const Tw tw2 = make_tw(t & ~15);

    float acc = 0.f;
    __half2 cur[4], nxt[4];
#pragma unroll
    for (int q = 0; q < 4; ++q) cur[q] = gimg[(size_t)vbase * 256 + t + (q << 6)];
    for (int j = 0; j < 4; ++j) {
        const int v = vbase + j;
        if (j < 3) {
#pragma unroll
            for (int q = 0; q < 4; ++q) nxt[q] = gimg[(size_t)(v + 1) * 256 + t + (q << 6)];
        }
        float2 z[4];
#pragma unroll
        for (int q = 0; q < 4; ++q) z[q] = __half22float2(cur[q]);
        fft_stage0(z[0], z[1], z[2], z[3], Xb[w], t, tw0);
        fft_stage_mid<2>(Xb[w], t, tw1);
        fft_stage_mid<4>(Xb[w], t, tw2);
        float2 d0, d1, d2, d3;  // d_q = W[t + 64q]
        fft_stage3_reg(Xb[w], t, d0, d1, d2, d3);
        float ssum = 0.f;
        if (v == 0) {  // wave-uniform rare path: needs W[-u]; LDS round trip
            Xb[w][PIDX(t)] = d0;
            Xb[w][PIDX(t + 64)] = d1;
            Xb[w][PIDX(t + 128)] = d2;
            Xb[w][PIDX(t + 192)] = d3;
            WAVE_SYNC();
#pragma unroll
            for (int q = 0; q < 4; ++q) {
                const int u = t + 64 * q;
                const float2 zu = Xb[w][PIDX(u)];
                const float2 zm = Xb[w][PIDX((256 - u) & 255)];
                // C_A[u] = 0.5(W[u]+conj(W[-u]));  C_B[u] = -0.5i(W[u]-conj(W[-u]))
                const float ax = 0.5f * (zu.x + zm.x), ay = 0.5f * (zu.y - zm.y);
                const float bx = 0.5f * (zu.y + zm.y), by = -0.5f * (zu.x - zm.x);
                ssum += sqrtf(ax * ax + ay * ay) + sqrtf(bx * bx + by * by);
            }
        } else {
            ssum = 2.f * (sqrtf(d0.x * d0.x + d0.y * d0.y) + sqrtf(d1.x * d1.x + d1.y * d1.y) +
                          sqrtf(d2.x * d2.x + d2.y * d2.y) + sqrtf(d3.x * d3.x + d3.y * d3.y));
        }
        acc += ssum;
#pragma unroll
        for (int q = 0; q < 4; ++q) cur[q] = nxt[q];
        WAVE_SYNC();  // Xb fully consumed before next column's stage-0 writes
    }
#pragma unroll
    for (int off = 32; off; off >>= 1) acc += __shfl_down(acc, off);
    if (t == 0) wsum[w] = acc;
    __syncthreads();
    if (tid == 0) {
        const int img = img0 + blockIdx.y;
        partial[img * 8 + blockIdx.x] = wsum[0] + wsum[1] + wsum[2] + wsum[3];
        __threadfence();  // release partial before counting
        const int old = atomicAdd(counter, 1);
        isLast = (old == COLBLK_TOTAL - 1) ? 1 : 0;
    }
    __syncthreads();
    // Final reduction by the single last-arriving block (deterministic order).
    if (isLast) {
        __shared__ float ps[96];
        if (tid == 0) __threadfence();  // acquire all partials
        __syncthreads();
        if (tid < 96) {
            float s = 0.f;
            const float* p = partial + tid * 24;  // pair tid: imgs 3p..3p+2, 8 chunks each
            for (int e = 0; e < 24; ++e) s += p[e];
            ps[tid] = s;
        }
        __syncthreads();
        if (tid < 64) {  // wave 0: tid = 2i+k
            const float inv = 1.f / 196608.f;  // mean over C*H*W
            const float dap = ps[tid >> 1] * inv;
            const float dan = ps[32 + tid] * inv + 1e-7f;
            float val = dap / dan;
#pragma unroll
            for (int off = 32; off; off >>= 1) val += __shfl_down(val, off);
            if (tid == 0) out[0] = val * (1.f / 64.f);  // / (MULTI_N_NUM * B)
        }
    }
}

extern "C" void kernel_launch(void* const* d_in, const int* in_sizes, int n_in,
                              void* d_out, int out_size, void* d_ws, size_t ws_size,
                              hipStream_t stream) {
    const float* A = (const float*)d_in[0];
    const float* P = (const float*)d_in[1];
    const float* N = (const float*)d_in[2];
    const int* negIdx = (const int*)d_in[3];

    float* partial = (float*)d_ws;                    // 2304 floats = 9216 B
    int* counter = (int*)((char*)d_ws + 9216);        // 4 B
    __half2* inter = (__half2*)((char*)d_ws + 40960);
    const size_t perImg = (size_t)128 * 256 * sizeof(__half2);  // 131072 B
    size_t avail = ws_size > 40960 ? ws_size - 40960 : 0;
    int cap = (int)(avail / perImg);
    if (cap > N_IMG) cap = N_IMG;
    if (cap < 1) cap = 1;  // last resort

    for (int img0 = 0; img0 < N_IMG; img0 += cap) {
        const int nimg = (N_IMG - img0 < cap) ? (N_IMG - img0) : cap;
        dim3 g1(8, nimg);
        k_rowfft<<<g1, dim3(256), 0, stream>>>(A, P, N, negIdx, inter, img0, counter);
        dim3 g2(8, nimg);
        k_colfft<<<g2, dim3(256), 0, stream>>>(inter, partial, img0, counter, (float*)d_out);
    }
}

// Round 15
// 45.718 us; speedup vs baseline: 2.9306x; 2.0557x over previous
//
#include <hip/hip_runtime.h>
#include <hip/hip_fp16.h>
#include <math.h>

// Padded LDS index for FFT scratch: injective for e in [0,256) -> [0,271)
#define PIDX(e) ((e) + ((e) >> 4))

// Wave-local "sync": waves own disjoint LDS slices; same-wave DS ops are
// processed in order by the LDS pipe, so we only need a COMPILER fence.
#define WAVE_SYNC()                          \
    do {                                     \
        __builtin_amdgcn_wave_barrier();     \
        asm volatile("" ::: "memory");       \
    } while (0)

__device__ __forceinline__ float2 cadd(float2 a, float2 b) { return {a.x + b.x, a.y + b.y}; }
__device__ __forceinline__ float2 csub(float2 a, float2 b) { return {a.x - b.x, a.y - b.y}; }
__device__ __forceinline__ float2 cmul(float2 a, float2 b) {
    return {a.x * b.x - a.y * b.y, a.x * b.y + a.y * b.x};
}
__device__ __forceinline__ float2 shfl64(float2 v, int src) {
    return {__shfl(v.x, src), __shfl(v.y, src)};
}

// Radix-4 butterfly (DIF): d0..d3 from c0..c3.
#define BFLY4(c0, c1, c2, c3, d0, d1, d2, d3)            \
    {                                                    \
        float2 sa = cadd(c0, c2);                        \
        float2 sb = csub(c0, c2);                        \
        float2 sc = cadd(c1, c3);                        \
        float2 sd = {(c1).y - (c3).y, (c3).x - (c1).x}; \
        d0 = cadd(sa, sc);                               \
        d1 = cadd(sb, sd);                               \
        d2 = csub(sa, sc);                               \
        d3 = csub(sb, sd);                               \
    }

// Per-lane twiddle set for one stage (constant across all FFTs of the kernel).
struct Tw {
    float2 w1, w2, w3;
};
__device__ __forceinline__ Tw make_tw(int idx) {
    const float ang = -0.024543692606170259f * (float)idx;  // -(2pi/256)*idx
    float sy, cx;
    __sincosf(ang, &sy, &cx);
    Tw tw;
    tw.w1 = {cx, sy};
    tw.w2 = cmul(tw.w1, tw.w1);
    tw.w3 = cmul(tw.w2, tw.w1);
    return tw;
}

// Stage 0 (stride-64 partners, within-lane): registers -> LDS (natural order).
__device__ __forceinline__ void fft_stage0(float2 z0, float2 z1, float2 z2, float2 z3, float2* X,
                                           int t, const Tw& tw) {
    float2 d0, d1, d2, d3;
    BFLY4(z0, z1, z2, z3, d0, d1, d2, d3);
    const int ob = t << 2;
    X[PIDX(ob)] = d0;
    X[PIDX(ob + 1)] = cmul(tw.w1, d1);
    X[PIDX(ob + 2)] = cmul(tw.w2, d2);
    X[PIDX(ob + 3)] = cmul(tw.w3, d3);
    WAVE_SYNC();
}

// Middle stage (s=1: SH=2, s=2: SH=4), single LDS buffer: reads are always
// {t, t+64, t+128, t+192}; read-all -> fence -> write-all (same-wave DS order).
template <int SH>
__device__ __forceinline__ void fft_stage_mid(float2* X, int t, const Tw& tw) {
    float2 c0 = X[PIDX(t)];
    float2 c1 = X[PIDX(t + 64)];
    float2 c2 = X[PIDX(t + 128)];
    float2 c3 = X[PIDX(t + 192)];
    WAVE_SYNC();
    float2 d0, d1, d2, d3;
    BFLY4(c0, c1, c2, c3, d0, d1, d2, d3);
    const int mm = 1 << SH;
    const int jj = t >> SH;
    const int kk = t & (mm - 1);
    const int ob = kk + 4 * mm * jj;
    X[PIDX(ob)] = d0;
    X[PIDX(ob + mm)] = cmul(tw.w1, d1);
    X[PIDX(ob + 2 * mm)] = cmul(tw.w2, d2);
    X[PIDX(ob + 3 * mm)] = cmul(tw.w3, d3);
    WAVE_SYNC();
}

// Stage 3 (jj=0 -> identity twiddle): keep the result in registers.
// d_q = Z[t + 64q].
__device__ __forceinline__ void fft_stage3_reg(float2* X, int t, float2& d0, float2& d1,
                                               float2& d2, float2& d3) {
    float2 c0 = X[PIDX(t)];
    float2 c1 = X[PIDX(t + 64)];
    float2 c2 = X[PIDX(t + 128)];
    float2 c3 = X[PIDX(t + 192)];
    WAVE_SYNC();  // reads done before this buffer is overwritten by next stage0
    BFLY4(c0, c1, c2, c3, d0, d1, d2, d3);
}

// 16 strided dword loads: lane t gets element cols {t+64q} of rows r, r+1 for
// both inputs. Each instr reads 256B contiguous across the wave (coalesced).
__device__ __forceinline__ void load16(const float* __restrict__ abase,
                                       const float* __restrict__ sbase, int r, int t, float* a0,
                                       float* a1, float* s0, float* s1) {
#pragma unroll
    for (int q = 0; q < 4; ++q) {
        a0[q] = abase[(r << 8) + t + (q << 6)];
        a1[q] = abase[((r + 1) << 8) + t + (q << 6)];
        s0[q] = sbase[(r << 8) + t + (q << 6)];
        s1[q] = sbase[((r + 1) << 8) + t + (q << 6)];
    }
}

// Kernel 1: row FFTs of the real difference image, two rows per complex FFT.
// Output f16 spectra transposed [img][v][r], v in [0,128): v=0 packs (D[0],D[128]).
// grid = (8 row-chunks, nimg), block = 256 = 4 waves; 4 packed FFTs per wave,
// register prefetch, stage0+stage3 in registers, hoisted twiddles.
__global__ __launch_bounds__(256) void k_rowfft(const float* __restrict__ A,
                                                const float* __restrict__ P,
                                                const float* __restrict__ N,
                                                const int* __restrict__ negIdx,
                                                __half2* __restrict__ ws, int img0) {
    __shared__ float2 Xb[4][272];       // 8.7 KB (single-buffer FFT)
    __shared__ __half2 outT[128 * 33];  // 16.9 KB, stride 33 -> conflict-free

    const int img = img0 + blockIdx.y;
    const int pair = img / 3;
    const int ch = img - pair * 3;
    int i, jn;
    const float* S;
    if (pair < 32) {  // anchor-positive pairs: j == i
        i = pair;
        jn = pair;
        S = P;
    } else {  // anchor-negative pairs: j = neg_idx[i][k]
        const int t2 = pair - 32;
        i = t2 >> 1;
        jn = negIdx[(i << 1) + (t2 & 1)];
        S = N;
    }
    const float* abase = A + ((size_t)(i * 3 + ch) << 16);
    const float* sbase = S + ((size_t)(jn * 3 + ch) << 16);

    const int tid = threadIdx.x;
    const int w = tid >> 6;   // wave id
    const int t = tid & 63;   // lane
    const int r0 = blockIdx.x * 32;

    // Hoisted per-lane twiddles (constant for every FFT in this kernel).
    const Tw tw0 = make_tw(t);
    const Tw tw1 = make_tw(t & ~3);
    const Tw tw2 = make_tw(t & ~15);
    const int ridx = (64 - t) & 63;  // reversal shuffle index

    float pa0[4], pa1[4], ps0[4], ps1[4];
    load16(abase, sbase, r0 + 2 * w, t, pa0, pa1, ps0, ps1);

    for (int it = 0; it < 4; ++it) {
        const int slot = 2 * (it * 4 + w);  // even row slot in [0,32)
        float2 z[4];
#pragma unroll
        for (int q = 0; q < 4; ++q) z[q] = {pa0[q] - ps0[q], pa1[q] - ps1[q]};
        // prefetch next iteration's rows; flies under the whole FFT
        if (it < 3) load16(abase, sbase, r0 + 2 * ((it + 1) * 4 + w), t, pa0, pa1, ps0, ps1);
        fft_stage0(z[0], z[1], z[2], z[3], Xb[w], t, tw0);
        fft_stage_mid<2>(Xb[w], t, tw1);
        fft_stage_mid<4>(Xb[w], t, tw2);
        float2 d0, d1, d2, d3;  // d_q = Z[t + 64q]
        fft_stage3_reg(Xb[w], t, d0, d1, d2, d3);
        // Hermitian unpack (register/shuffle only):
        //   D_r[v] = 0.5*(Z[v] + conj(Z[-v]));  D_r1[v] = -0.5i*(Z[v] - conj(Z[-v]))
        const float2 m3 = shfl64(d3, ridx);  // Z[256-t] for t>=1
        const float2 m2 = shfl64(d2, ridx);  // Z[192-t] for t>=1
        if (t == 0) {
            // v=0 packs (D_r[0], D_r[128]) = (Re/Im Z[0], Re/Im Z[128])
            outT[slot] = __floats2half2_rn(d0.x, d2.x);
            outT[slot + 1] = __floats2half2_rn(d0.y, d2.y);
        } else {
            outT[t * 33 + slot] = __floats2half2_rn(0.5f * (d0.x + m3.x), 0.5f * (d0.y - m3.y));
            outT[t * 33 + slot + 1] =
                __floats2half2_rn(0.5f * (d0.y + m3.y), -0.5f * (d0.x - m3.x));
        }
        {  // v = t + 64;  m = Z[192-t] (lane 0: Z[192] = own d3)
            const int v = t + 64;
            const float2 mm2 = (t == 0) ? d3 : m2;
            outT[v * 33 + slot] = __floats2half2_rn(0.5f * (d1.x + mm2.x), 0.5f * (d1.y - mm2.y));
            outT[v * 33 + slot + 1] =
                __floats2half2_rn(0.5f * (d1.y + mm2.y), -0.5f * (d1.x - mm2.x));
        }
        WAVE_SYNC();  // outT slot writes complete before Xb reuse next iter
    }

    __syncthreads();  // all waves' outT slots complete

    // write [v][r0..r0+31] chunks: one float4 (4 half2) per thread per iter
    __half2* g = ws + (size_t)blockIdx.y * (128 * 256);
    for (int e = tid; e < 128 * 8; e += 256) {
        const int v = e >> 3, rl4 = (e & 7) << 2;
        float4 val;
        __half2* vp = (__half2*)&val;
#pragma unroll
        for (int k = 0; k < 4; ++k) vp[k] = outT[v * 33 + rl4 + k];
        *(float4*)(g + v * 256 + r0 + rl4) = val;
    }
}

// Kernel 2: column FFTs (complex 256-pt) + weighted magnitude sum.
// grid = (8, nimg), block = 256 = 4 waves; each wave owns 4 consecutive
// columns serially with register prefetch; stages 0 & 3 in registers,
// magnitudes own-lane (LDS-free) except the rare v==0 wave.
// v=0 is the packed real pair (col0, col128): weight 1; v>=1: weight 2.
__global__ __launch_bounds__(256) void k_colfft(const __half2* __restrict__ ws,
                                                float* __restrict__ partial, int img0) {
    __shared__ float2 Xb[4][272];  // 8.7 KB
    __shared__ float wsum[4];
    const int tid = threadIdx.x;
    const int w = tid >> 6, t = tid & 63;
    const int vbase = blockIdx.x * 16 + w * 4;  // [0,128)
    const __half2* gimg = ws + (size_t)blockIdx.y * (128 * 256);

    const Tw tw0 = make_tw(t);
    const Tw tw1 = make_tw(t & ~3);
    const Tw tw2 = make_tw(t & ~15);

    float acc = 0.f;
    __half2 cur[4], nxt[4];
#pragma unroll
    for (int q = 0; q < 4; ++q) cur[q] = gimg[(size_t)vbase * 256 + t + (q << 6)];
    for (int j = 0; j < 4; ++j) {
        const int v = vbase + j;
        if (j < 3) {
#pragma unroll
            for (int q = 0; q < 4; ++q) nxt[q] = gimg[(size_t)(v + 1) * 256 + t + (q << 6)];
        }
        float2 z[4];
#pragma unroll
        for (int q = 0; q < 4; ++q) z[q] = __half22float2(cur[q]);
        fft_stage0(z[0], z[1], z[2], z[3], Xb[w], t, tw0);
        fft_stage_mid<2>(Xb[w], t, tw1);
        fft_stage_mid<4>(Xb[w], t, tw2);
        float2 d0, d1, d2, d3;  // d_q = W[t + 64q]
        fft_stage3_reg(Xb[w], t, d0, d1, d2, d3);
        float ssum = 0.f;
        if (v == 0) {  // wave-uniform rare path: needs W[-u]; LDS round trip
            Xb[w][PIDX(t)] = d0;
            Xb[w][PIDX(t + 64)] = d1;
            Xb[w][PIDX(t + 128)] = d2;
            Xb[w][PIDX(t + 192)] = d3;
            WAVE_SYNC();
#pragma unroll
            for (int q = 0; q < 4; ++q) {
                const int u = t + 64 * q;
                const float2 zu = Xb[w][PIDX(u)];
                const float2 zm = Xb[w][PIDX((256 - u) & 255)];
                // C_A[u] = 0.5(W[u]+conj(W[-u]));  C_B[u] = -0.5i(W[u]-conj(W[-u]))
                const float ax = 0.5f * (zu.x + zm.x), ay = 0.5f * (zu.y - zm.y);
                const float bx = 0.5f * (zu.y + zm.y), by = -0.5f * (zu.x - zm.x);
                ssum += sqrtf(ax * ax + ay * ay) + sqrtf(bx * bx + by * by);
            }
        } else {
            ssum = 2.f * (sqrtf(d0.x * d0.x + d0.y * d0.y) + sqrtf(d1.x * d1.x + d1.y * d1.y) +
                          sqrtf(d2.x * d2.x + d2.y * d2.y) + sqrtf(d3.x * d3.x + d3.y * d3.y));
        }
        acc += ssum;
#pragma unroll
        for (int q = 0; q < 4; ++q) cur[q] = nxt[q];
        WAVE_SYNC();  // Xb fully consumed before next column's stage-0 writes
    }
#pragma unroll
    for (int off = 32; off; off >>= 1) acc += __shfl_down(acc, off);
    if (t == 0) wsum[w] = acc;
    __syncthreads();
    if (tid == 0) {
        const int img = img0 + blockIdx.y;
        partial[img * 8 + blockIdx.x] = wsum[0] + wsum[1] + wsum[2] + wsum[3];
    }
}

// partial layout [img][chunk=8], img-major: pair p's 3 images = 24 consecutive floats.
// pairSum[0..31] = sum|FFT(a-p)| per i;  pairSum[32 + 2i + k] = sum|FFT(a_i - n_j)|
__global__ void k_final(const float* __restrict__ partial, float* __restrict__ out) {
    __shared__ float ps[96];
    const int t = threadIdx.x;  // 128 threads
    if (t < 96) {
        float s = 0.f;
        const float* p = partial + t * 24;
        for (int e = 0; e < 24; ++e) s += p[e];
        ps[t] = s;
    }
    __syncthreads();
    if (t < 64) {  // wave 0: t = 2i+k
        const float inv = 1.f / 196608.f;  // mean over C*H*W
        const float dap = ps[t >> 1] * inv;
        const float dan = ps[32 + t] * inv + 1e-7f;
        float val = dap / dan;
#pragma unroll
        for (int off = 32; off; off >>= 1) val += __shfl_down(val, off);
        if (t == 0) out[0] = val * (1.f / 64.f);  // / (MULTI_N_NUM * B)
    }
}

extern "C" void kernel_launch(void* const* d_in, const int* in_sizes, int n_in,
                              void* d_out, int out_size, void* d_ws, size_t ws_size,
                              hipStream_t stream) {
    const float* A = (const float*)d_in[0];
    const float* P = (const float*)d_in[1];
    const float* N = (const float*)d_in[2];
    const int* negIdx = (const int*)d_in[3];

    float* partial = (float*)d_ws;  // 288*8 floats = 9216 B
    __half2* inter = (__half2*)((char*)d_ws + 40960);
    const size_t perImg = (size_t)128 * 256 * sizeof(__half2);  // 131072 B
    size_t avail = ws_size > 40960 ? ws_size - 40960 : 0;
    int cap = (int)(avail / perImg);
    if (cap > 288) cap = 288;
    if (cap < 1) cap = 1;  // last resort

    for (int img0 = 0; img0 < 288; img0 += cap) {
        const int nimg = (288 - img0 < cap) ? (288 - img0) : cap;
        dim3 g1(8, nimg);
        k_rowfft<<<g1, dim3(256), 0, stream>>>(A, P, N, negIdx, inter, img0);
        dim3 g2(8, nimg);
        k_colfft<<<g2, dim3(256), 0, stream>>>(inter, partial, img0);
    }
    k_final<<<1, 128, 0, stream>>>(partial, (float*)d_out);
}